// Round 4
// baseline (192.792 us; speedup 1.0000x reference)
//
#include <hip/hip_runtime.h>

// B=8, C=256, H=W=48 -> N=2304, k=4 -> CK=64
#define BATCH 8
#define CIN   256
#define NPIX  2304
#define CKD   64
#define NIT   (NPIX / 16)  // 144 16-pixel tiles
#define NIC   (NPIX / 32)  // 72 32-i chunks
#define NJB   (NPIX / 64)  // 36 64-j blocks
#define NCH   (NPIX / 64)  // 36 64-i chunks

typedef _Float16 f16;
typedef __attribute__((ext_vector_type(4))) _Float16 f16x4;
typedef __attribute__((ext_vector_type(8))) _Float16 f16x8;
typedef __attribute__((ext_vector_type(4))) float    f32x4;

// Blocked layouts (tile = 512 f16 = 1KB, lane ln owns bytes ln*8..ln*8+15):
//   q_blk[b][IT][ks][512]  A-frag tiles: pix = IT*16 + (ln&15), ck = ks*32+(ln>>4)*8..
//   k_blk[b][JT][ks][512]  B-frag tiles, same internal structure
//   u_blk[b][CT][ic][512]  A-frag tiles: c = CT*16+(ln&15), i = ic*32+(ln>>4)*8..

// ---------------------------------------------------------------------------
// Cast all conv weights fp32 -> f16. Wqk = [qw (64x256); kw (64x256)].
// ---------------------------------------------------------------------------
__global__ __launch_bounds__(256) void cast_w(
    const float* __restrict__ qw, const float* __restrict__ kw,
    const float* __restrict__ vw, const float* __restrict__ gw,
    f16* __restrict__ Wqk, f16* __restrict__ Wv, f16* __restrict__ Wg)
{
    int idx = (blockIdx.x * 256 + threadIdx.x) * 4;
    const float* src;
    f16* dst;
    if (idx < 16384)      { src = qw + idx;           dst = Wqk + idx; }
    else if (idx < 32768) { src = kw + (idx - 16384); dst = Wqk + idx; }
    else if (idx < 98304) { src = vw + (idx - 32768); dst = Wv + (idx - 32768); }
    else                  { src = gw + (idx - 98304); dst = Wg + (idx - 98304); }
    float4 v = *(const float4*)src;
    f16x4 h = { (f16)v.x, (f16)v.y, (f16)v.z, (f16)v.w };
    *(f16x4*)dst = h;
}

// ---------------------------------------------------------------------------
// x[b][c][n] fp32 -> xT[b][n][c] f16 (LDS transpose). Tile 64c x 64n.
// ---------------------------------------------------------------------------
__global__ __launch_bounds__(256) void cast_xT(
    const float* __restrict__ x, f16* __restrict__ xT)
{
    __shared__ float s[64][65];
    const int t = threadIdx.x;
    const int n0 = blockIdx.x * 64, c0 = blockIdx.y * 64, b = blockIdx.z;
    const float* xb = x + ((size_t)b * CIN + c0) * NPIX + n0;

    const int cl = t >> 4, ng = (t & 15) * 4;
    #pragma unroll
    for (int p = 0; p < 4; ++p) {
        float4 v = *(const float4*)(xb + (size_t)(cl + 16 * p) * NPIX + ng);
        s[cl + 16 * p][ng + 0] = v.x;
        s[cl + 16 * p][ng + 1] = v.y;
        s[cl + 16 * p][ng + 2] = v.z;
        s[cl + 16 * p][ng + 3] = v.w;
    }
    __syncthreads();
    const int nl = t >> 2, cs = (t & 3) * 16;
    f16 h[16];
    #pragma unroll
    for (int j = 0; j < 16; ++j) h[j] = (f16)s[cs + j][nl];
    f16* gp = &xT[((size_t)b * NPIX + n0 + nl) * CIN + c0 + cs];
    *(f16x8*)gp       = *(f16x8*)&h[0];
    *(f16x8*)(gp + 8) = *(f16x8*)&h[8];
}

// ---------------------------------------------------------------------------
// q & k conv via MFMA; outputs q_blk / k_blk (frag-blocked) via LDS repack.
// grid (N/32, B), block 256.
// ---------------------------------------------------------------------------
__global__ __launch_bounds__(256) void qk_conv_mfma(
    const f16* __restrict__ xT, const f16* __restrict__ Wqk,
    const float* __restrict__ qbias, const float* __restrict__ kbias,
    f16* __restrict__ q_blk, f16* __restrict__ k_blk)
{
    __shared__ __align__(16) f16 us[32 * 136];   // [n_local][o], stride 272B
    const int t = threadIdx.x, w = t >> 6, lane = t & 63;
    const int quad = lane >> 4, l16 = lane & 15;
    const int wm = w & 1, wn = w >> 1;
    const int n0 = blockIdx.x * 32, b = blockIdx.y;

    const f16* bp = xT + ((size_t)b * NPIX + n0 + 16 * wn + l16) * CIN;
    const f16* ap = Wqk + (size_t)(64 * wm + l16) * CIN;

    f32x4 acc[4];
    #pragma unroll
    for (int mt = 0; mt < 4; ++mt) acc[mt] = (f32x4){0.f, 0.f, 0.f, 0.f};

    #pragma unroll
    for (int kk = 0; kk < CIN; kk += 32) {
        f16x8 bf = *(const f16x8*)(bp + kk + quad * 8);
        #pragma unroll
        for (int mt = 0; mt < 4; ++mt) {
            f16x8 af = *(const f16x8*)(ap + (size_t)mt * 16 * CIN + kk + quad * 8);
            acc[mt] = __builtin_amdgcn_mfma_f32_16x16x32_f16(af, bf, acc[mt], 0, 0, 0);
        }
    }
    const float* bias = wm ? kbias - 64 : qbias;   // o-indexed
    #pragma unroll
    for (int mt = 0; mt < 4; ++mt) {
        int ob = 64 * wm + 16 * mt + quad * 4;
        #pragma unroll
        for (int r = 0; r < 4; ++r)
            us[(16 * wn + l16) * 136 + ob + r] = (f16)(acc[mt][r] + bias[ob + r]);
    }
    __syncthreads();
    // blocked stores: thread t -> (ks = t>>7, nt = (t>>6)&1, ln = t&63)
    {
        int ks2 = t >> 7, nt = (t >> 6) & 1, ln = t & 63;
        const f16* usr = &us[(nt * 16 + (ln & 15)) * 136 + ks2 * 32 + (ln >> 4) * 8];
        size_t base = (((size_t)b * NIT + (n0 >> 4) + nt) * 2 + ks2) * 512 + ln * 8;
        *(f16x8*)&q_blk[base] = *(const f16x8*)(usr);
        *(f16x8*)&k_blk[base] = *(const f16x8*)(usr + 64);
    }
}

// ---------------------------------------------------------------------------
// S-only energy pass: partial row sums of f16(exp(q_i.k_j)) per 64-j block.
// Blocked (contiguous) frag loads; no Et store. grid (N/64 j, N/128 i, B).
// ---------------------------------------------------------------------------
#define ESL 136
__global__ __launch_bounds__(256) void energy_S(
    const f16* __restrict__ q_blk, const f16* __restrict__ k_blk,
    float* __restrict__ Pred)
{
    __shared__ __align__(16) f16 es[64 * ESL];
    __shared__ float red2[2][128];
    const int t    = threadIdx.x;
    const int w    = t >> 6, lane = t & 63;
    const int quad = lane >> 4, l16 = lane & 15;
    const int j0 = blockIdx.x * 64, i0 = blockIdx.y * 128, b = blockIdx.z;
    const size_t ln8 = (size_t)lane * 8;
    const f16* qb = q_blk + (size_t)b * NIT * 2 * 512 + ln8;

    f32x4 acc[8];
    #pragma unroll
    for (int mt = 0; mt < 8; ++mt) acc[mt] = (f32x4){0.f, 0.f, 0.f, 0.f};

    #pragma unroll
    for (int ks = 0; ks < 2; ++ks) {
        f16x8 bf = *(const f16x8*)(k_blk +
            (((size_t)b * NIT + (j0 >> 4) + w) * 2 + ks) * 512 + ln8);
        #pragma unroll
        for (int mt = 0; mt < 8; ++mt) {
            f16x8 af = *(const f16x8*)(qb + ((size_t)((i0 >> 4) + mt) * 2 + ks) * 512);
            acc[mt] = __builtin_amdgcn_mfma_f32_16x16x32_f16(af, bf, acc[mt], 0, 0, 0);
        }
    }

    // exp -> LDS es[j][i] (lane: j = 16w+l16, i = 16mt+quad*4+r)
    #pragma unroll
    for (int mt = 0; mt < 8; ++mt) {
        f16x4 h = { (f16)__expf(acc[mt][0]), (f16)__expf(acc[mt][1]),
                    (f16)__expf(acc[mt][2]), (f16)__expf(acc[mt][3]) };
        *(f16x4*)&es[(16 * w + l16) * ESL + 16 * mt + quad * 4] = h;
    }
    __syncthreads();
    {
        int i = t & 127, jq = t >> 7;
        float s = 0.f;
        #pragma unroll
        for (int jj = 0; jj < 32; ++jj)
            s += (float)es[(jq * 32 + jj) * ESL + i];
        red2[jq][i] = s;
    }
    __syncthreads();
    if (t < 128)
        Pred[((size_t)blockIdx.x * BATCH + b) * NPIX + i0 + t] =
            red2[0][t] + red2[1][t];
}

// ---------------------------------------------------------------------------
// S[b,i] = sum over 36 j-block partials (coalesced). grid BN/256.
// ---------------------------------------------------------------------------
__global__ __launch_bounds__(256) void reduce_S(
    const float* __restrict__ Pred, float* __restrict__ S)
{
    const size_t BN = (size_t)BATCH * NPIX;
    size_t idx = (size_t)blockIdx.x * 256 + threadIdx.x;
    float s = 0.f;
    #pragma unroll
    for (int jb = 0; jb < NJB; ++jb)
        s += Pred[(size_t)jb * BN + idx];
    S[idx] = s;
}

// ---------------------------------------------------------------------------
// v conv via MFMA, fused bias + 1/S scale; output u_blk (A-frag-blocked).
// Tile 128(c) x 64(i), BK=32. grid (N/64, C/128, B), block 256.
// ---------------------------------------------------------------------------
__global__ __launch_bounds__(256) void v_conv_mfma(
    const f16* __restrict__ xT, const f16* __restrict__ Wv,
    const float* __restrict__ vbias, const float* __restrict__ S,
    f16* __restrict__ u_blk)
{
    __shared__ __align__(16) f16 smem[9216];   // As 128*40 | Bs 64*40; reused as us 128*72
    f16* As = smem;
    f16* Bs = smem + 128 * 40;
    f16* us = smem;
    const int t = threadIdx.x, w = t >> 6, lane = t & 63;
    const int quad = lane >> 4, l16 = lane & 15;
    const int wm = w & 1, wn = w >> 1;
    const int i0 = blockIdx.x * 64, c0 = blockIdx.y * 128, b = blockIdx.z;
    const int sub = t >> 2, le = t & 3;
    const f16* srcA = Wv + (size_t)(c0 + sub) * CIN + le * 8;
    const f16* srcB = xT + ((size_t)b * NPIX + i0 + sub) * CIN + le * 8;
    const int ldsw = sub * 40 + le * 8;

    f32x4 acc[4][2];
    #pragma unroll
    for (int mt = 0; mt < 4; ++mt)
        #pragma unroll
        for (int nt = 0; nt < 2; ++nt)
            acc[mt][nt] = (f32x4){0.f, 0.f, 0.f, 0.f};

    for (int kk = 0; kk < CIN; kk += 32) {
        f16x8 ta0 = *(const f16x8*)(srcA + kk);
        f16x8 ta1 = *(const f16x8*)(srcA + (size_t)64 * CIN + kk);
        f16x8 tb0 = *(const f16x8*)(srcB + kk);
        __syncthreads();
        *(f16x8*)&As[ldsw]           = ta0;
        *(f16x8*)&As[64 * 40 + ldsw] = ta1;
        *(f16x8*)&Bs[ldsw]           = tb0;
        __syncthreads();
        f16x8 af[4], bf[2];
        #pragma unroll
        for (int mt = 0; mt < 4; ++mt)
            af[mt] = *(const f16x8*)&As[(64 * wm + 16 * mt + l16) * 40 + quad * 8];
        #pragma unroll
        for (int nt = 0; nt < 2; ++nt)
            bf[nt] = *(const f16x8*)&Bs[(32 * wn + 16 * nt + l16) * 40 + quad * 8];
        #pragma unroll
        for (int mt = 0; mt < 4; ++mt)
            #pragma unroll
            for (int nt = 0; nt < 2; ++nt)
                acc[mt][nt] = __builtin_amdgcn_mfma_f32_16x16x32_f16(
                    af[mt], bf[nt], acc[mt][nt], 0, 0, 0);
    }

    __syncthreads();   // As/Bs dead; reuse as us[c][i] (stride 72)
    #pragma unroll
    for (int nt = 0; nt < 2; ++nt) {
        int i = 32 * wn + 16 * nt + l16;
        float is = 1.0f / S[(size_t)b * NPIX + i0 + i];
        #pragma unroll
        for (int mt = 0; mt < 4; ++mt)
            #pragma unroll
            for (int r = 0; r < 4; ++r) {
                int c = 64 * wm + 16 * mt + quad * 4 + r;
                us[c * 72 + i] = (f16)((acc[mt][nt][r] + vbias[c0 + c]) * is);
            }
    }
    __syncthreads();
    #pragma unroll
    for (int p = 0; p < 4; ++p) {
        int g  = t + 256 * p;
        int ct = g >> 7, ic = (g >> 6) & 1, ln = g & 63;
        f16x8 v = *(const f16x8*)&us[(ct * 16 + (ln & 15)) * 72 + ic * 32 + (ln >> 4) * 8];
        *(f16x8*)&u_blk[(((size_t)b * 16 + (c0 >> 4) + ct) * NIC + (i0 >> 5) + ic) * 512 + ln * 8] = v;
    }
}

// ---------------------------------------------------------------------------
// FUSED bmm: o1[b,j,c] = sum_i u[c,i] * f16(exp(q_i.k_j))
// Block 64j x 256c x HALF the i-range, 8 waves. XCD-batch affinity (b=bid&7).
// i-SPLIT x2: grid 576 -> 4.5 waves/SIMD, independently-phased blocks per CU
// so one block's MFMA burst overlaps another's exp/barrier phase.
// Each half writes a partial o1 (o1A / o1B); gamma_conv sums them.
// Register-pipelined U/Q loads; raw s_barrier + lgkmcnt(0) (no vmcnt drain).
// setprio(1) around stage-2 MFMA cluster (cross-block arbitration).
// grid 576, block 512.
// ---------------------------------------------------------------------------
__global__ __launch_bounds__(512, 4) void fused_bmm(
    const f16* __restrict__ q_blk, const f16* __restrict__ k_blk,
    const f16* __restrict__ u_blk, f16* __restrict__ o1A, f16* __restrict__ o1B)
{
    // es[buf][jt*2+isub][512]: B-frag tiles (16j x 32i) of f16(exp(E))
    __shared__ __align__(16) f16 es[2][8][512];
    const int t = threadIdx.x, w = t >> 6, lane = t & 63;
    const int quad = lane >> 4, l16 = lane & 15;
    const int bid = blockIdx.x;
    const int b   = bid & 7;           // XCD-batch affinity
    const int r   = bid >> 3;          // 0..71
    const int j0  = (r >> 1) * 64;
    const int half = r & 1;
    const int ic0 = half * (NCH / 2);  // 0 or 18
    const int icN = ic0 + NCH / 2;
    f16* __restrict__ o1h = half ? o1B : o1A;
    const size_t ln8 = (size_t)lane * 8;

    const f16* qb = q_blk + (size_t)b * NIT * 2 * 512 + ln8;
    const f16* ub = u_blk + (size_t)b * 16 * NIC * 512 + ln8;

    const int iw = w >> 1;       // stage-1 i-16-tile index (0..3) in 64-i chunk
    const int jh = w & 1;        // stage-1 j-tiles: jh and jh+2

    // k-frags for this wave's two stage-1 j-tiles, resident for whole kernel
    f16x8 kf[2][2];
    #pragma unroll
    for (int jj = 0; jj < 2; ++jj)
        #pragma unroll
        for (int ks = 0; ks < 2; ++ks)
            kf[jj][ks] = *(const f16x8*)(k_blk +
                (((size_t)b * NIT + (j0 >> 4) + jh + 2 * jj) * 2 + ks) * 512 + ln8);

    const int CT0 = w * 2;       // this wave's two u c-tiles (c = 32w..32w+31)
    // stage-1 write: intra-tile offset (blocked B-frag layout)
    const int woff = ((iw & 1) * 2 + (quad >> 1)) * 128 + l16 * 8 + (quad & 1) * 4;
    const int et0 = jh * 2 + (iw >> 1);        // es tile for jt=jh
    const int et1 = (jh + 2) * 2 + (iw >> 1);  // es tile for jt=jh+2

    f32x4 acc[2][4];   // [c-tile mt][j-tile jt]
    #pragma unroll
    for (int mt = 0; mt < 2; ++mt)
        #pragma unroll
        for (int jt = 0; jt < 4; ++jt)
            acc[mt][jt] = (f32x4){0.f, 0.f, 0.f, 0.f};

#define QLD(ic, ks)  (*(const f16x8*)(qb + ((size_t)((ic) * 4 + iw) * 2 + (ks)) * 512))
#define ULD(ct, ic, is) (*(const f16x8*)(ub + ((size_t)(CT0 + (ct)) * NIC + (ic) * 2 + (is)) * 512))

#define STAGE1(q0, q1, buf) do {                                              \
    f32x4 e0 = (f32x4){0.f, 0.f, 0.f, 0.f};                                   \
    f32x4 e1 = (f32x4){0.f, 0.f, 0.f, 0.f};                                   \
    e0 = __builtin_amdgcn_mfma_f32_16x16x32_f16(q0, kf[0][0], e0, 0, 0, 0);   \
    e0 = __builtin_amdgcn_mfma_f32_16x16x32_f16(q1, kf[0][1], e0, 0, 0, 0);   \
    e1 = __builtin_amdgcn_mfma_f32_16x16x32_f16(q0, kf[1][0], e1, 0, 0, 0);   \
    e1 = __builtin_amdgcn_mfma_f32_16x16x32_f16(q1, kf[1][1], e1, 0, 0, 0);   \
    f16x4 h0 = { (f16)__expf(e0[0]), (f16)__expf(e0[1]),                      \
                 (f16)__expf(e0[2]), (f16)__expf(e0[3]) };                    \
    f16x4 h1 = { (f16)__expf(e1[0]), (f16)__expf(e1[1]),                      \
                 (f16)__expf(e1[2]), (f16)__expf(e1[3]) };                    \
    *(f16x4*)&es[buf][et0][woff] = h0;                                        \
    *(f16x4*)&es[buf][et1][woff] = h1;                                        \
} while (0)

#define STAGE2(buf, u00, u01, u10, u11) do {                                  \
    __builtin_amdgcn_s_setprio(1);                                            \
    _Pragma("unroll")                                                         \
    for (int jt = 0; jt < 4; ++jt) {                                          \
        f16x8 bf0 = *(const f16x8*)&es[buf][jt * 2 + 0][ln8];                 \
        acc[0][jt] = __builtin_amdgcn_mfma_f32_16x16x32_f16(u00, bf0, acc[0][jt], 0, 0, 0); \
        acc[1][jt] = __builtin_amdgcn_mfma_f32_16x16x32_f16(u10, bf0, acc[1][jt], 0, 0, 0); \
        f16x8 bf1 = *(const f16x8*)&es[buf][jt * 2 + 1][ln8];                 \
        acc[0][jt] = __builtin_amdgcn_mfma_f32_16x16x32_f16(u01, bf1, acc[0][jt], 0, 0, 0); \
        acc[1][jt] = __builtin_amdgcn_mfma_f32_16x16x32_f16(u11, bf1, acc[1][jt], 0, 0, 0); \
    }                                                                         \
    __builtin_amdgcn_s_setprio(0);                                            \
} while (0)

#define BAR() do {                                                            \
    asm volatile("s_waitcnt lgkmcnt(0)" ::: "memory");                        \
    __builtin_amdgcn_s_barrier();                                             \
} while (0)

    // ---- prologue: E(ic0) -> es[0]; prefetch U(ic0), Q(ic0+1)
    f16x8 qA0 = QLD(ic0, 0), qA1 = QLD(ic0, 1);
    f16x8 uA0 = ULD(0, ic0, 0), uA1 = ULD(0, ic0, 1);
    f16x8 uA2 = ULD(1, ic0, 0), uA3 = ULD(1, ic0, 1);
    f16x8 qB0 = QLD(ic0 + 1, 0), qB1 = QLD(ic0 + 1, 1);
    STAGE1(qA0, qA1, 0);
    BAR();

    f16x8 uB0, uB1, uB2, uB3;
    for (int ic = ic0; ic < icN; ic += 2) {
        const int i1 = ic + 1;
        const int i2 = (ic + 2 < icN) ? ic + 2 : icN - 1;
        const int i3 = (ic + 3 < icN) ? ic + 3 : icN - 1;
        // ---- even half: stage2(ic) on es[0]/uA; stage1 E(ic+1)->es[1]
        uB0 = ULD(0, i1, 0); uB1 = ULD(0, i1, 1);
        uB2 = ULD(1, i1, 0); uB3 = ULD(1, i1, 1);
        qA0 = QLD(i2, 0); qA1 = QLD(i2, 1);       // for E(ic+2)
        STAGE2(0, uA0, uA1, uA2, uA3);
        STAGE1(qB0, qB1, 1);
        BAR();
        // ---- odd half: stage2(ic+1) on es[1]/uB; stage1 E(ic+2)->es[0]
        uA0 = ULD(0, i2, 0); uA1 = ULD(0, i2, 1);
        uA2 = ULD(1, i2, 0); uA3 = ULD(1, i2, 1);
        qB0 = QLD(i3, 0); qB1 = QLD(i3, 1);       // for E(ic+3)
        STAGE2(1, uB0, uB1, uB2, uB3);
        if (ic + 2 < icN) STAGE1(qA0, qA1, 0);
        BAR();
    }

#undef QLD
#undef ULD
#undef STAGE1
#undef STAGE2
#undef BAR

    #pragma unroll
    for (int mt = 0; mt < 2; ++mt) {
        int cb = 32 * w + 16 * mt + quad * 4;
        #pragma unroll
        for (int jt = 0; jt < 4; ++jt) {
            int j = j0 + 16 * jt + l16;
            f16x4 h2 = { (f16)acc[mt][jt][0], (f16)acc[mt][jt][1],
                         (f16)acc[mt][jt][2], (f16)acc[mt][jt][3] };
            *(f16x4*)&o1h[((size_t)b * NPIX + j) * CIN + cb] = h2;
        }
    }
}

// ---------------------------------------------------------------------------
// Gamma conv via MFMA: out[b,o,j] = sum_c Wg[o,c]*(o1A+o1B)[c,j] + gb[o].
// Sums the two fused_bmm i-half partials on load. fp32 out.
// Tile 128(o) x 64(j), BK=32. grid (N/64, C/128, B), block 256.
// ---------------------------------------------------------------------------
__global__ __launch_bounds__(256) void gamma_conv_mfma(
    const f16* __restrict__ o1A, const f16* __restrict__ o1B,
    const f16* __restrict__ Wg,
    const float* __restrict__ gbias, float* __restrict__ out)
{
    __shared__ __align__(16) f16 As[128 * 40];
    __shared__ __align__(16) f16 Bs[64 * 40];
    const int t = threadIdx.x, w = t >> 6, lane = t & 63;
    const int quad = lane >> 4, l16 = lane & 15;
    const int wm = w & 1, wn = w >> 1;
    const int j0 = blockIdx.x * 64, o0 = blockIdx.y * 128, b = blockIdx.z;
    const int sub = t >> 2, le = t & 3;
    const f16* srcA  = Wg + (size_t)(o0 + sub) * CIN + le * 8;
    const size_t boff = ((size_t)b * NPIX + j0 + sub) * CIN + le * 8;
    const f16* srcB  = o1A + boff;
    const f16* srcB2 = o1B + boff;
    const int ldsw = sub * 40 + le * 8;

    f32x4 acc[4][2];
    #pragma unroll
    for (int mt = 0; mt < 4; ++mt)
        #pragma unroll
        for (int nt = 0; nt < 2; ++nt)
            acc[mt][nt] = (f32x4){0.f, 0.f, 0.f, 0.f};

    for (int kk = 0; kk < CIN; kk += 32) {
        f16x8 ta0 = *(const f16x8*)(srcA + kk);
        f16x8 ta1 = *(const f16x8*)(srcA + (size_t)64 * CIN + kk);
        f16x8 tb0 = *(const f16x8*)(srcB + kk);
        f16x8 tb1 = *(const f16x8*)(srcB2 + kk);
        tb0 = tb0 + tb1;   // sum i-half partials (elementwise f16)
        __syncthreads();
        *(f16x8*)&As[ldsw]           = ta0;
        *(f16x8*)&As[64 * 40 + ldsw] = ta1;
        *(f16x8*)&Bs[ldsw]           = tb0;
        __syncthreads();
        f16x8 af[4], bf[2];
        #pragma unroll
        for (int mt = 0; mt < 4; ++mt)
            af[mt] = *(const f16x8*)&As[(64 * wm + 16 * mt + l16) * 40 + quad * 8];
        #pragma unroll
        for (int nt = 0; nt < 2; ++nt)
            bf[nt] = *(const f16x8*)&Bs[(32 * wn + 16 * nt + l16) * 40 + quad * 8];
        #pragma unroll
        for (int mt = 0; mt < 4; ++mt)
            #pragma unroll
            for (int nt = 0; nt < 2; ++nt)
                acc[mt][nt] = __builtin_amdgcn_mfma_f32_16x16x32_f16(
                    af[mt], bf[nt], acc[mt][nt], 0, 0, 0);
    }

    #pragma unroll
    for (int mt = 0; mt < 4; ++mt)
        #pragma unroll
        for (int r = 0; r < 4; ++r) {
            int o = o0 + 64 * wm + 16 * mt + quad * 4 + r;
            float bv = gbias[o];
            #pragma unroll
            for (int nt = 0; nt < 2; ++nt) {
                int j = j0 + 32 * wn + 16 * nt + l16;
                out[((size_t)b * CIN + o) * NPIX + j] = acc[mt][nt][r] + bv;
            }
        }
}

// ---------------------------------------------------------------------------
extern "C" void kernel_launch(void* const* d_in, const int* in_sizes, int n_in,
                              void* d_out, int out_size, void* d_ws, size_t ws_size,
                              hipStream_t stream) {
    const float* x   = (const float*)d_in[0];
    const float* qw  = (const float*)d_in[1];
    const float* qbv = (const float*)d_in[2];
    const float* kw  = (const float*)d_in[3];
    const float* kbv = (const float*)d_in[4];
    const float* vw  = (const float*)d_in[5];
    const float* vbv = (const float*)d_in[6];
    const float* gw  = (const float*)d_in[7];
    const float* gbv = (const float*)d_in[8];
    float* out = (float*)d_out;

    const size_t BCN  = (size_t)BATCH * CIN * NPIX;   // 4,718,592
    const size_t BN   = (size_t)BATCH * NPIX;         // 18,432
    const size_t BNCK = (size_t)BATCH * NPIX * CKD;   // 1,179,648

    // ws layout (~36 MB). NOTE: xT is dead after v_conv_mfma; fused_bmm
    // reuses its space as the second o1 partial (o1B).
    f16* q_blk = (f16*)d_ws;          // 2.36 MB
    f16* k_blk = q_blk + BNCK;        // 2.36 MB
    f16* u_blk = k_blk + BNCK;        // 9.44 MB
    f16* xT    = u_blk + BCN;         // 9.44 MB (o1B after v_conv)
    f16* o1T   = xT + BCN;            // 9.44 MB (o1A)
    f16* Wqk   = o1T + BCN;
    f16* Wv    = Wqk + 128 * 256;
    f16* Wg    = Wv + 256 * 256;
    float* S   = (float*)(Wg + 256 * 256);   // 0.07 MB
    float* Pred= S + BN;                      // 2.65 MB

    cast_w<<<160, 256, 0, stream>>>(qw, kw, vw, gw, Wqk, Wv, Wg);
    cast_xT<<<dim3(NPIX / 64, CIN / 64, BATCH), 256, 0, stream>>>(x, xT);
    qk_conv_mfma<<<dim3(NPIX / 32, BATCH), 256, 0, stream>>>(xT, Wqk, qbv, kbv, q_blk, k_blk);
    energy_S<<<dim3(NPIX / 64, NPIX / 128, BATCH), 256, 0, stream>>>(q_blk, k_blk, Pred);
    reduce_S<<<(int)(BN / 256), 256, 0, stream>>>(Pred, S);
    v_conv_mfma<<<dim3(NPIX / 64, CIN / 128, BATCH), 256, 0, stream>>>(xT, Wv, vbv, S, u_blk);
    fused_bmm<<<NJB * BATCH * 2, 512, 0, stream>>>(q_blk, k_blk, u_blk, o1T, xT);
    gamma_conv_mfma<<<dim3(NPIX / 64, CIN / 128, BATCH), 256, 0, stream>>>(o1T, xT, Wg, gbv, out);
}

// Round 5
// 190.815 us; speedup vs baseline: 1.0104x; 1.0104x over previous
//
#include <hip/hip_runtime.h>

// B=8, C=256, H=W=48 -> N=2304, k=4 -> CK=64
#define BATCH 8
#define CIN   256
#define NPIX  2304
#define CKD   64
#define NIT   (NPIX / 16)  // 144 16-pixel tiles
#define NIC   (NPIX / 32)  // 72 32-i chunks
#define NJB   (NPIX / 64)  // 36 64-j blocks
#define NQ    4            // i-quarters in fused_bmm
#define ICQ   (NIC / NQ)   // 18 32-i chunks per quarter
#define IT16Q (NIT / NQ)   // 36 16-i tiles per quarter

typedef _Float16 f16;
typedef __attribute__((ext_vector_type(4))) _Float16 f16x4;
typedef __attribute__((ext_vector_type(8))) _Float16 f16x8;
typedef __attribute__((ext_vector_type(4))) float    f32x4;

// Blocked layouts (tile = 512 f16 = 1KB, lane ln owns bytes ln*8..ln*8+15):
//   q_blk[b][IT][ks][512]  A-frag tiles: pix = IT*16 + (ln&15), ck = ks*32+(ln>>4)*8..
//   k_blk[b][JT][ks][512]  B-frag tiles, same internal structure
//   u_blk[b][CT][ic][512]  A-frag tiles: c = CT*16+(ln&15), i = ic*32+(ln>>4)*8..

// ---------------------------------------------------------------------------
// Cast all conv weights fp32 -> f16. Wqk = [qw (64x256); kw (64x256)].
// ---------------------------------------------------------------------------
__global__ __launch_bounds__(256) void cast_w(
    const float* __restrict__ qw, const float* __restrict__ kw,
    const float* __restrict__ vw, const float* __restrict__ gw,
    f16* __restrict__ Wqk, f16* __restrict__ Wv, f16* __restrict__ Wg)
{
    int idx = (blockIdx.x * 256 + threadIdx.x) * 4;
    const float* src;
    f16* dst;
    if (idx < 16384)      { src = qw + idx;           dst = Wqk + idx; }
    else if (idx < 32768) { src = kw + (idx - 16384); dst = Wqk + idx; }
    else if (idx < 98304) { src = vw + (idx - 32768); dst = Wv + (idx - 32768); }
    else                  { src = gw + (idx - 98304); dst = Wg + (idx - 98304); }
    float4 v = *(const float4*)src;
    f16x4 h = { (f16)v.x, (f16)v.y, (f16)v.z, (f16)v.w };
    *(f16x4*)dst = h;
}

// ---------------------------------------------------------------------------
// x[b][c][n] fp32 -> xT[b][n][c] f16 (LDS transpose). Tile 64c x 64n.
// ---------------------------------------------------------------------------
__global__ __launch_bounds__(256) void cast_xT(
    const float* __restrict__ x, f16* __restrict__ xT)
{
    __shared__ float s[64][65];
    const int t = threadIdx.x;
    const int n0 = blockIdx.x * 64, c0 = blockIdx.y * 64, b = blockIdx.z;
    const float* xb = x + ((size_t)b * CIN + c0) * NPIX + n0;

    const int cl = t >> 4, ng = (t & 15) * 4;
    #pragma unroll
    for (int p = 0; p < 4; ++p) {
        float4 v = *(const float4*)(xb + (size_t)(cl + 16 * p) * NPIX + ng);
        s[cl + 16 * p][ng + 0] = v.x;
        s[cl + 16 * p][ng + 1] = v.y;
        s[cl + 16 * p][ng + 2] = v.z;
        s[cl + 16 * p][ng + 3] = v.w;
    }
    __syncthreads();
    const int nl = t >> 2, cs = (t & 3) * 16;
    f16 h[16];
    #pragma unroll
    for (int j = 0; j < 16; ++j) h[j] = (f16)s[cs + j][nl];
    f16* gp = &xT[((size_t)b * NPIX + n0 + nl) * CIN + c0 + cs];
    *(f16x8*)gp       = *(f16x8*)&h[0];
    *(f16x8*)(gp + 8) = *(f16x8*)&h[8];
}

// ---------------------------------------------------------------------------
// q & k conv via MFMA; outputs q_blk / k_blk (frag-blocked) via LDS repack.
// grid (N/32, B), block 256.
// ---------------------------------------------------------------------------
__global__ __launch_bounds__(256) void qk_conv_mfma(
    const f16* __restrict__ xT, const f16* __restrict__ Wqk,
    const float* __restrict__ qbias, const float* __restrict__ kbias,
    f16* __restrict__ q_blk, f16* __restrict__ k_blk)
{
    __shared__ __align__(16) f16 us[32 * 136];   // [n_local][o], stride 272B
    const int t = threadIdx.x, w = t >> 6, lane = t & 63;
    const int quad = lane >> 4, l16 = lane & 15;
    const int wm = w & 1, wn = w >> 1;
    const int n0 = blockIdx.x * 32, b = blockIdx.y;

    const f16* bp = xT + ((size_t)b * NPIX + n0 + 16 * wn + l16) * CIN;
    const f16* ap = Wqk + (size_t)(64 * wm + l16) * CIN;

    f32x4 acc[4];
    #pragma unroll
    for (int mt = 0; mt < 4; ++mt) acc[mt] = (f32x4){0.f, 0.f, 0.f, 0.f};

    #pragma unroll
    for (int kk = 0; kk < CIN; kk += 32) {
        f16x8 bf = *(const f16x8*)(bp + kk + quad * 8);
        #pragma unroll
        for (int mt = 0; mt < 4; ++mt) {
            f16x8 af = *(const f16x8*)(ap + (size_t)mt * 16 * CIN + kk + quad * 8);
            acc[mt] = __builtin_amdgcn_mfma_f32_16x16x32_f16(af, bf, acc[mt], 0, 0, 0);
        }
    }
    const float* bias = wm ? kbias - 64 : qbias;   // o-indexed
    #pragma unroll
    for (int mt = 0; mt < 4; ++mt) {
        int ob = 64 * wm + 16 * mt + quad * 4;
        #pragma unroll
        for (int r = 0; r < 4; ++r)
            us[(16 * wn + l16) * 136 + ob + r] = (f16)(acc[mt][r] + bias[ob + r]);
    }
    __syncthreads();
    // blocked stores: thread t -> (ks = t>>7, nt = (t>>6)&1, ln = t&63)
    {
        int ks2 = t >> 7, nt = (t >> 6) & 1, ln = t & 63;
        const f16* usr = &us[(nt * 16 + (ln & 15)) * 136 + ks2 * 32 + (ln >> 4) * 8];
        size_t base = (((size_t)b * NIT + (n0 >> 4) + nt) * 2 + ks2) * 512 + ln * 8;
        *(f16x8*)&q_blk[base] = *(const f16x8*)(usr);
        *(f16x8*)&k_blk[base] = *(const f16x8*)(usr + 64);
    }
}

// ---------------------------------------------------------------------------
// S-only energy pass: partial row sums of f16(exp(q_i.k_j)) per 64-j block.
// Blocked (contiguous) frag loads; no Et store. grid (N/64 j, N/128 i, B).
// ---------------------------------------------------------------------------
#define ESL 136
__global__ __launch_bounds__(256) void energy_S(
    const f16* __restrict__ q_blk, const f16* __restrict__ k_blk,
    float* __restrict__ Pred)
{
    __shared__ __align__(16) f16 es[64 * ESL];
    __shared__ float red2[2][128];
    const int t    = threadIdx.x;
    const int w    = t >> 6, lane = t & 63;
    const int quad = lane >> 4, l16 = lane & 15;
    const int j0 = blockIdx.x * 64, i0 = blockIdx.y * 128, b = blockIdx.z;
    const size_t ln8 = (size_t)lane * 8;
    const f16* qb = q_blk + (size_t)b * NIT * 2 * 512 + ln8;

    f32x4 acc[8];
    #pragma unroll
    for (int mt = 0; mt < 8; ++mt) acc[mt] = (f32x4){0.f, 0.f, 0.f, 0.f};

    #pragma unroll
    for (int ks = 0; ks < 2; ++ks) {
        f16x8 bf = *(const f16x8*)(k_blk +
            (((size_t)b * NIT + (j0 >> 4) + w) * 2 + ks) * 512 + ln8);
        #pragma unroll
        for (int mt = 0; mt < 8; ++mt) {
            f16x8 af = *(const f16x8*)(qb + ((size_t)((i0 >> 4) + mt) * 2 + ks) * 512);
            acc[mt] = __builtin_amdgcn_mfma_f32_16x16x32_f16(af, bf, acc[mt], 0, 0, 0);
        }
    }

    // exp -> LDS es[j][i] (lane: j = 16w+l16, i = 16mt+quad*4+r)
    #pragma unroll
    for (int mt = 0; mt < 8; ++mt) {
        f16x4 h = { (f16)__expf(acc[mt][0]), (f16)__expf(acc[mt][1]),
                    (f16)__expf(acc[mt][2]), (f16)__expf(acc[mt][3]) };
        *(f16x4*)&es[(16 * w + l16) * ESL + 16 * mt + quad * 4] = h;
    }
    __syncthreads();
    {
        int i = t & 127, jq = t >> 7;
        float s = 0.f;
        #pragma unroll
        for (int jj = 0; jj < 32; ++jj)
            s += (float)es[(jq * 32 + jj) * ESL + i];
        red2[jq][i] = s;
    }
    __syncthreads();
    if (t < 128)
        Pred[((size_t)blockIdx.x * BATCH + b) * NPIX + i0 + t] =
            red2[0][t] + red2[1][t];
}

// ---------------------------------------------------------------------------
// S[b,i] = sum over 36 j-block partials (coalesced). grid BN/256.
// ---------------------------------------------------------------------------
__global__ __launch_bounds__(256) void reduce_S(
    const float* __restrict__ Pred, float* __restrict__ S)
{
    const size_t BN = (size_t)BATCH * NPIX;
    size_t idx = (size_t)blockIdx.x * 256 + threadIdx.x;
    float s = 0.f;
    #pragma unroll
    for (int jb = 0; jb < NJB; ++jb)
        s += Pred[(size_t)jb * BN + idx];
    S[idx] = s;
}

// ---------------------------------------------------------------------------
// v conv via MFMA, fused bias + 1/S scale; output u_blk (A-frag-blocked).
// Tile 128(c) x 64(i), BK=32. grid (N/64, C/128, B), block 256.
// ---------------------------------------------------------------------------
__global__ __launch_bounds__(256) void v_conv_mfma(
    const f16* __restrict__ xT, const f16* __restrict__ Wv,
    const float* __restrict__ vbias, const float* __restrict__ S,
    f16* __restrict__ u_blk)
{
    __shared__ __align__(16) f16 smem[9216];   // As 128*40 | Bs 64*40; reused as us 128*72
    f16* As = smem;
    f16* Bs = smem + 128 * 40;
    f16* us = smem;
    const int t = threadIdx.x, w = t >> 6, lane = t & 63;
    const int quad = lane >> 4, l16 = lane & 15;
    const int wm = w & 1, wn = w >> 1;
    const int i0 = blockIdx.x * 64, c0 = blockIdx.y * 128, b = blockIdx.z;
    const int sub = t >> 2, le = t & 3;
    const f16* srcA = Wv + (size_t)(c0 + sub) * CIN + le * 8;
    const f16* srcB = xT + ((size_t)b * NPIX + i0 + sub) * CIN + le * 8;
    const int ldsw = sub * 40 + le * 8;

    f32x4 acc[4][2];
    #pragma unroll
    for (int mt = 0; mt < 4; ++mt)
        #pragma unroll
        for (int nt = 0; nt < 2; ++nt)
            acc[mt][nt] = (f32x4){0.f, 0.f, 0.f, 0.f};

    for (int kk = 0; kk < CIN; kk += 32) {
        f16x8 ta0 = *(const f16x8*)(srcA + kk);
        f16x8 ta1 = *(const f16x8*)(srcA + (size_t)64 * CIN + kk);
        f16x8 tb0 = *(const f16x8*)(srcB + kk);
        __syncthreads();
        *(f16x8*)&As[ldsw]           = ta0;
        *(f16x8*)&As[64 * 40 + ldsw] = ta1;
        *(f16x8*)&Bs[ldsw]           = tb0;
        __syncthreads();
        f16x8 af[4], bf[2];
        #pragma unroll
        for (int mt = 0; mt < 4; ++mt)
            af[mt] = *(const f16x8*)&As[(64 * wm + 16 * mt + l16) * 40 + quad * 8];
        #pragma unroll
        for (int nt = 0; nt < 2; ++nt)
            bf[nt] = *(const f16x8*)&Bs[(32 * wn + 16 * nt + l16) * 40 + quad * 8];
        #pragma unroll
        for (int mt = 0; mt < 4; ++mt)
            #pragma unroll
            for (int nt = 0; nt < 2; ++nt)
                acc[mt][nt] = __builtin_amdgcn_mfma_f32_16x16x32_f16(
                    af[mt], bf[nt], acc[mt][nt], 0, 0, 0);
    }

    __syncthreads();   // As/Bs dead; reuse as us[c][i] (stride 72)
    #pragma unroll
    for (int nt = 0; nt < 2; ++nt) {
        int i = 32 * wn + 16 * nt + l16;
        float is = 1.0f / S[(size_t)b * NPIX + i0 + i];
        #pragma unroll
        for (int mt = 0; mt < 4; ++mt)
            #pragma unroll
            for (int r = 0; r < 4; ++r) {
                int c = 64 * wm + 16 * mt + quad * 4 + r;
                us[c * 72 + i] = (f16)((acc[mt][nt][r] + vbias[c0 + c]) * is);
            }
    }
    __syncthreads();
    #pragma unroll
    for (int p = 0; p < 4; ++p) {
        int g  = t + 256 * p;
        int ct = g >> 7, ic = (g >> 6) & 1, ln = g & 63;
        f16x8 v = *(const f16x8*)&us[(ct * 16 + (ln & 15)) * 72 + ic * 32 + (ln >> 4) * 8];
        *(f16x8*)&u_blk[(((size_t)b * 16 + (c0 >> 4) + ct) * NIC + (i0 >> 5) + ic) * 512 + ln * 8] = v;
    }
}

// ---------------------------------------------------------------------------
// FUSED bmm v5: o1[b,j,c] = sum_i u[c,i] * f16(exp(q_i.k_j))
// Block 64j x 256c x 576i (one i-QUARTER), 8 waves. XCD-batch affine.
// TWO-PHASE, ONE BARRIER:
//  phase 1: all exp(E) B-frag tiles for (64j x 576i) -> es LDS (72 KB).
//           Per wave: 9 i16-tiles x 2 j-tiles = 36 MFMA + 72 exp.
//  phase 2: barrier-free MFMA stream: per wave 18 chunks x 8 MFMA = 144
//           MFMA with 2-deep register-prefetched u frags. setprio(1).
// 4 o1 partials (one per quarter); gamma_conv sums them in f32.
// grid 36*4*8 = 1152, block 512, 2 blocks/CU (72 KB dynamic LDS).
// ---------------------------------------------------------------------------
__global__ __launch_bounds__(512, 4) void fused_bmm(
    const f16* __restrict__ q_blk, const f16* __restrict__ k_blk,
    const f16* __restrict__ u_blk,
    f16* __restrict__ o1A, f16* __restrict__ o1B,
    f16* __restrict__ o1C, f16* __restrict__ o1D)
{
    extern __shared__ __align__(16) f16 es[];   // [72 tiles][512] = 72 KB
    const int t = threadIdx.x, w = t >> 6, lane = t & 63;
    const int quad = lane >> 4, l16 = lane & 15;
    const int bid = blockIdx.x;
    const int b   = bid & 7;           // XCD-batch affinity
    const int r   = bid >> 3;          // 0..143
    const int q   = r & 3;             // i-quarter
    const int jb  = r >> 2;            // 0..35
    const int j0  = jb * 64;
    f16* __restrict__ o1h = (q == 0) ? o1A : (q == 1) ? o1B : (q == 2) ? o1C : o1D;
    const size_t ln8 = (size_t)lane * 8;

    const f16* qb = q_blk + (size_t)b * NIT * 2 * 512 + ln8;
    const f16* ub = u_blk + (size_t)b * 16 * NIC * 512 + ln8;

    const int iw0 = w >> 1;      // phase-1 i16-tile start (stride 4)
    const int jh  = w & 1;       // phase-1 j-tiles: jh and jh+2

    // k-frags for this wave's two phase-1 j-tiles
    f16x8 kf[2][2];
    #pragma unroll
    for (int jj = 0; jj < 2; ++jj)
        #pragma unroll
        for (int ks = 0; ks < 2; ++ks)
            kf[jj][ks] = *(const f16x8*)(k_blk +
                (((size_t)b * NIT + (j0 >> 4) + jh + 2 * jj) * 2 + ks) * 512 + ln8);

    const int CT0 = w * 2;       // this wave's two u c-tiles (c = 32w..32w+31)

    // ---- phase 1: all E tiles of this (64j x 576i) region -> es
    #pragma unroll
    for (int s = 0; s < 9; ++s) {
        const int i16 = iw0 + 4 * s;            // local i16-tile 0..35
        const int gi  = q * IT16Q + i16;        // global i16-tile
        f16x8 q0 = *(const f16x8*)(qb + ((size_t)gi * 2 + 0) * 512);
        f16x8 q1 = *(const f16x8*)(qb + ((size_t)gi * 2 + 1) * 512);
        f32x4 e0 = (f32x4){0.f, 0.f, 0.f, 0.f};
        f32x4 e1 = (f32x4){0.f, 0.f, 0.f, 0.f};
        e0 = __builtin_amdgcn_mfma_f32_16x16x32_f16(q0, kf[0][0], e0, 0, 0, 0);
        e0 = __builtin_amdgcn_mfma_f32_16x16x32_f16(q1, kf[0][1], e0, 0, 0, 0);
        e1 = __builtin_amdgcn_mfma_f32_16x16x32_f16(q0, kf[1][0], e1, 0, 0, 0);
        e1 = __builtin_amdgcn_mfma_f32_16x16x32_f16(q1, kf[1][1], e1, 0, 0, 0);
        f16x4 h0 = { (f16)__expf(e0[0]), (f16)__expf(e0[1]),
                     (f16)__expf(e0[2]), (f16)__expf(e0[3]) };
        f16x4 h1 = { (f16)__expf(e1[0]), (f16)__expf(e1[1]),
                     (f16)__expf(e1[2]), (f16)__expf(e1[3]) };
        const int woff = ((i16 & 1) * 2 + (quad >> 1)) * 128 + l16 * 8 + (quad & 1) * 4;
        const int tb   = (i16 >> 1) * 4;        // B-frag tile row (32i chunk)
        *(f16x4*)&es[(size_t)(tb + jh) * 512 + woff]     = h0;
        *(f16x4*)&es[(size_t)(tb + jh + 2) * 512 + woff] = h1;
    }

    // ---- prefetch first two u chunks, then barrier (loads stay in flight)
    const int g0 = q * ICQ;
#define ULD(ct, icg) (*(const f16x8*)(ub + ((size_t)(CT0 + (ct)) * NIC + (icg)) * 512))
    f16x8 ua = ULD(0, g0),     ub2 = ULD(1, g0);
    f16x8 na = ULD(0, g0 + 1), nb  = ULD(1, g0 + 1);
    asm volatile("s_waitcnt lgkmcnt(0)" ::: "memory");
    __builtin_amdgcn_s_barrier();

    // ---- phase 2: barrier-free MFMA stream over 18 32-i chunks
    f32x4 acc[2][4];   // [c-tile][j-tile]
    #pragma unroll
    for (int mt = 0; mt < 2; ++mt)
        #pragma unroll
        for (int jt = 0; jt < 4; ++jt)
            acc[mt][jt] = (f32x4){0.f, 0.f, 0.f, 0.f};

    __builtin_amdgcn_s_setprio(1);
    for (int ic2 = 0; ic2 < ICQ; ++ic2) {
        f16x8 fa, fb2;
        if (ic2 + 2 < ICQ) { fa = ULD(0, g0 + ic2 + 2); fb2 = ULD(1, g0 + ic2 + 2); }
        #pragma unroll
        for (int jt = 0; jt < 4; ++jt) {
            f16x8 bf = *(const f16x8*)&es[(size_t)(ic2 * 4 + jt) * 512 + ln8];
            acc[0][jt] = __builtin_amdgcn_mfma_f32_16x16x32_f16(ua,  bf, acc[0][jt], 0, 0, 0);
            acc[1][jt] = __builtin_amdgcn_mfma_f32_16x16x32_f16(ub2, bf, acc[1][jt], 0, 0, 0);
        }
        ua = na; ub2 = nb; na = fa; nb = fb2;
    }
    __builtin_amdgcn_s_setprio(0);
#undef ULD

    #pragma unroll
    for (int mt = 0; mt < 2; ++mt) {
        int cb = 32 * w + 16 * mt + quad * 4;
        #pragma unroll
        for (int jt = 0; jt < 4; ++jt) {
            int j = j0 + 16 * jt + l16;
            f16x4 h2 = { (f16)acc[mt][jt][0], (f16)acc[mt][jt][1],
                         (f16)acc[mt][jt][2], (f16)acc[mt][jt][3] };
            *(f16x4*)&o1h[((size_t)b * NPIX + j) * CIN + cb] = h2;
        }
    }
}

// ---------------------------------------------------------------------------
// Gamma conv via MFMA: out[b,o,j] = sum_c Wg[o,c]*(sum of 4 o1 partials)[c,j]
// + gb[o]. Partials summed in f32 on load. fp32 out.
// Tile 128(o) x 64(j), BK=32. grid (N/64, C/128, B), block 256.
// ---------------------------------------------------------------------------
__global__ __launch_bounds__(256) void gamma_conv_mfma(
    const f16* __restrict__ o1A, const f16* __restrict__ o1B,
    const f16* __restrict__ o1C, const f16* __restrict__ o1D,
    const f16* __restrict__ Wg,
    const float* __restrict__ gbias, float* __restrict__ out)
{
    __shared__ __align__(16) f16 As[128 * 40];
    __shared__ __align__(16) f16 Bs[64 * 40];
    const int t = threadIdx.x, w = t >> 6, lane = t & 63;
    const int quad = lane >> 4, l16 = lane & 15;
    const int wm = w & 1, wn = w >> 1;
    const int j0 = blockIdx.x * 64, o0 = blockIdx.y * 128, b = blockIdx.z;
    const int sub = t >> 2, le = t & 3;
    const f16* srcA  = Wg + (size_t)(o0 + sub) * CIN + le * 8;
    const size_t boff = ((size_t)b * NPIX + j0 + sub) * CIN + le * 8;
    const int ldsw = sub * 40 + le * 8;

    f32x4 acc[4][2];
    #pragma unroll
    for (int mt = 0; mt < 4; ++mt)
        #pragma unroll
        for (int nt = 0; nt < 2; ++nt)
            acc[mt][nt] = (f32x4){0.f, 0.f, 0.f, 0.f};

    for (int kk = 0; kk < CIN; kk += 32) {
        f16x8 ta0 = *(const f16x8*)(srcA + kk);
        f16x8 ta1 = *(const f16x8*)(srcA + (size_t)64 * CIN + kk);
        f16x8 t0 = *(const f16x8*)(o1A + boff + kk);
        f16x8 t1 = *(const f16x8*)(o1B + boff + kk);
        f16x8 t2 = *(const f16x8*)(o1C + boff + kk);
        f16x8 t3 = *(const f16x8*)(o1D + boff + kk);
        f16x8 tb0;
        #pragma unroll
        for (int e = 0; e < 8; ++e)
            tb0[e] = (f16)(((float)t0[e] + (float)t1[e]) +
                           ((float)t2[e] + (float)t3[e]));
        __syncthreads();
        *(f16x8*)&As[ldsw]           = ta0;
        *(f16x8*)&As[64 * 40 + ldsw] = ta1;
        *(f16x8*)&Bs[ldsw]           = tb0;
        __syncthreads();
        f16x8 af[4], bf[2];
        #pragma unroll
        for (int mt = 0; mt < 4; ++mt)
            af[mt] = *(const f16x8*)&As[(64 * wm + 16 * mt + l16) * 40 + quad * 8];
        #pragma unroll
        for (int nt = 0; nt < 2; ++nt)
            bf[nt] = *(const f16x8*)&Bs[(32 * wn + 16 * nt + l16) * 40 + quad * 8];
        #pragma unroll
        for (int mt = 0; mt < 4; ++mt)
            #pragma unroll
            for (int nt = 0; nt < 2; ++nt)
                acc[mt][nt] = __builtin_amdgcn_mfma_f32_16x16x32_f16(
                    af[mt], bf[nt], acc[mt][nt], 0, 0, 0);
    }

    #pragma unroll
    for (int mt = 0; mt < 4; ++mt)
        #pragma unroll
        for (int r = 0; r < 4; ++r) {
            int o = o0 + 64 * wm + 16 * mt + quad * 4 + r;
            float bv = gbias[o];
            #pragma unroll
            for (int nt = 0; nt < 2; ++nt) {
                int j = j0 + 32 * wn + 16 * nt + l16;
                out[((size_t)b * CIN + o) * NPIX + j] = acc[mt][nt][r] + bv;
            }
        }
}

// ---------------------------------------------------------------------------
extern "C" void kernel_launch(void* const* d_in, const int* in_sizes, int n_in,
                              void* d_out, int out_size, void* d_ws, size_t ws_size,
                              hipStream_t stream) {
    const float* x   = (const float*)d_in[0];
    const float* qw  = (const float*)d_in[1];
    const float* qbv = (const float*)d_in[2];
    const float* kw  = (const float*)d_in[3];
    const float* kbv = (const float*)d_in[4];
    const float* vw  = (const float*)d_in[5];
    const float* vbv = (const float*)d_in[6];
    const float* gw  = (const float*)d_in[7];
    const float* gbv = (const float*)d_in[8];
    float* out = (float*)d_out;

    const size_t BCN  = (size_t)BATCH * CIN * NPIX;   // 4,718,592
    const size_t BN   = (size_t)BATCH * NPIX;         // 18,432
    const size_t BNCK = (size_t)BATCH * NPIX * CKD;   // 1,179,648

    // ws layout (~56 MB). xT is dead after v_conv_mfma -> reused as o1B.
    f16* q_blk = (f16*)d_ws;          // 2.36 MB
    f16* k_blk = q_blk + BNCK;        // 2.36 MB
    f16* u_blk = k_blk + BNCK;        // 9.44 MB
    f16* xT    = u_blk + BCN;         // 9.44 MB (o1B after v_conv)
    f16* o1T   = xT + BCN;            // 9.44 MB (o1A)
    f16* Wqk   = o1T + BCN;
    f16* Wv    = Wqk + 128 * 256;
    f16* Wg    = Wv + 256 * 256;
    float* S   = (float*)(Wg + 256 * 256);   // 0.07 MB
    float* Pred= S + BN;                      // 2.65 MB
    f16* o1C   = (f16*)(Pred + (size_t)NJB * BN);  // 9.44 MB
    f16* o1D   = o1C + BCN;                         // 9.44 MB

    cast_w<<<160, 256, 0, stream>>>(qw, kw, vw, gw, Wqk, Wv, Wg);
    cast_xT<<<dim3(NPIX / 64, CIN / 64, BATCH), 256, 0, stream>>>(x, xT);
    qk_conv_mfma<<<dim3(NPIX / 32, BATCH), 256, 0, stream>>>(xT, Wqk, qbv, kbv, q_blk, k_blk);
    energy_S<<<dim3(NPIX / 64, NPIX / 128, BATCH), 256, 0, stream>>>(q_blk, k_blk, Pred);
    reduce_S<<<(int)(BN / 256), 256, 0, stream>>>(Pred, S);
    v_conv_mfma<<<dim3(NPIX / 64, CIN / 128, BATCH), 256, 0, stream>>>(xT, Wv, vbv, S, u_blk);
    fused_bmm<<<NJB * NQ * BATCH, 512, 72 * 1024, stream>>>(
        q_blk, k_blk, u_blk, o1T, xT, o1C, o1D);
    gamma_conv_mfma<<<dim3(NPIX / 64, CIN / 128, BATCH), 256, 0, stream>>>(
        o1T, xT, o1C, o1D, Wg, gbv, out);
}